// Round 7
// baseline (671.691 us; speedup 1.0000x reference)
//
#include <hip/hip_runtime.h>

typedef _Float16 hf;
typedef _Float16 hf8 __attribute__((ext_vector_type(8)));
typedef float f32x4 __attribute__((ext_vector_type(4)));

static constexpr int BATCH = 4;
static constexpr int TPTS  = 65536;
static constexpr int NPTS  = BATCH * TPTS;   // 262144
static constexpr int R3    = 32768;
static constexpr int NVOX  = BATCH * R3;     // 131072

// fragment-linear f16 weight buffers (units of hf) inside d_out scratch.
static constexpr int OFF_WPOS = 0;         // K=64(pad 60), N=256: 2048 chunks
static constexpr int OFF_W0   = 16384;     // 5 x (K=256,N=128)
static constexpr int OFF_W1   = 180224;    // 5 x (K=128,N=128)
static constexpr int OFF_WSC  = 262144;    // 5 x (K=256,N=128)
static constexpr int OFF_WC   = 425984;    // K=128,N=128
static constexpr int NCHUNKS  = 55296;

__device__ constexpr int kpat(int g, int j) { return (j & 3) + 4 * g + 16 * (j >> 2); }

#define MFMA16(a, b, c) __builtin_amdgcn_mfma_f32_16x16x32_f16((a), (b), (c), 0, 0, 0)

__device__ inline hf8 relu8(hf8 a) {
#pragma unroll
  for (int i = 0; i < 8; ++i) a[i] = (a[i] > (hf)0) ? a[i] : (hf)0;
  return a;
}
__device__ inline f32x4 splat4(float v) {
  f32x4 r; r[0] = v; r[1] = v; r[2] = v; r[3] = v; return r;
}
__device__ inline hf8 ldfrag(const hf* __restrict__ base, int kc, int nt, int NT, int lane) {
  return *(const hf8*)(base + (((size_t)(kc * NT + nt) * 64 + lane) << 3));
}

// ---------------- weight fragment prep --------------------------------------
__global__ __launch_bounds__(256) void k_prep(
    const float* __restrict__ wpos, const float* __restrict__ w0,
    const float* __restrict__ w1,  const float* __restrict__ wsc,
    const float* __restrict__ wc,  hf* __restrict__ fr)
{
  const int cid = blockIdx.x * 256 + threadIdx.x;
  if (cid >= NCHUNKS) return;
  const float* src; hf* dst; int NT, N, kmax, loc;
  if (cid < 2048) {
    src = wpos; dst = fr + OFF_WPOS; NT = 16; N = 256; kmax = 60; loc = cid;
  } else if (cid < 22528) {
    int l5 = cid - 2048; int i = l5 >> 12; loc = l5 & 4095;
    src = w0 + (size_t)i * 32768; dst = fr + OFF_W0 + (size_t)i * 32768;
    NT = 8; N = 128; kmax = 256;
  } else if (cid < 32768) {
    int l5 = cid - 22528; int i = l5 >> 11; loc = l5 & 2047;
    src = w1 + (size_t)i * 16384; dst = fr + OFF_W1 + (size_t)i * 16384;
    NT = 8; N = 128; kmax = 128;
  } else if (cid < 53248) {
    int l5 = cid - 32768; int i = l5 >> 12; loc = l5 & 4095;
    src = wsc + (size_t)i * 32768; dst = fr + OFF_WSC + (size_t)i * 32768;
    NT = 8; N = 128; kmax = 256;
  } else {
    loc = cid - 53248; src = wc; dst = fr + OFF_WC; NT = 8; N = 128; kmax = 128;
  }
  const int lane = loc & 63;
  const int rest = loc >> 6;
  const int nt = rest % NT, kc = rest / NT;
  const int g = lane >> 4;
  const int n = nt * 16 + (lane & 15);
  union { hf8 h; hf f[8]; } o;
#pragma unroll
  for (int j = 0; j < 8; ++j) {
    int k = kc * 32 + kpat(g, j);
    o.f[j] = (k < kmax) ? (hf)src[(size_t)k * N + n] : (hf)0;
  }
  *(hf8*)(dst + ((size_t)loc << 3)) = o.h;
}

// ---------------- voxel index + count (fused) --------------------------------
__global__ __launch_bounds__(256) void k_idxcnt(
    const float* __restrict__ p, int* __restrict__ idxbuf, int* __restrict__ cnt)
{
  const int t = blockIdx.x * 256 + threadIdx.x;
  const float px = p[(size_t)t * 3 + 0];
  const float py = p[(size_t)t * 3 + 1];
  const float pz = p[(size_t)t * 3 + 2];
  float nx = fminf(fmaxf(px / 1.101f + 0.5f, 0.0f), 0.999f);
  float ny = fminf(fmaxf(py / 1.101f + 0.5f, 0.0f), 0.999f);
  float nz = fminf(fmaxf(pz / 1.101f + 0.5f, 0.0f), 0.999f);
  const int iv = (int)(nx * 32.f) + 32 * (int)(ny * 32.f) + 1024 * (int)(nz * 32.f);
  idxbuf[t] = iv;
  atomicAdd(&cnt[((t >> 16) << 15) | iv], 1);
}

__global__ __launch_bounds__(256) void k_scan(
    const int* __restrict__ cnt, int* __restrict__ start, int* __restrict__ total)
{
  __shared__ int s[256];
  __shared__ int base_s;
  const int tid = threadIdx.x;
  const int v0 = blockIdx.x * 512;
  const int a = cnt[v0 + 2 * tid], b = cnt[v0 + 2 * tid + 1];
  const int sum = a + b;
  s[tid] = sum;
  __syncthreads();
  for (int off = 1; off < 256; off <<= 1) {
    int x = (tid >= off) ? s[tid - off] : 0;
    __syncthreads();
    s[tid] += x;
    __syncthreads();
  }
  if (tid == 255) base_s = atomicAdd(total, s[255]);
  __syncthreads();
  const int excl = base_s + s[tid] - sum;
  start[v0 + 2 * tid]     = excl;
  start[v0 + 2 * tid + 1] = excl + a;
}

// fill: advance start[bv] to END; record sorted slot (spos, in-place over
// idxbuf) and voxel per sorted slot (svox).
__global__ __launch_bounds__(256) void k_fill(
    int* __restrict__ idxbuf, int* __restrict__ start, int* __restrict__ svox)
{
  const int t = blockIdx.x * 256 + threadIdx.x;
  const int bv = ((t >> 16) << 15) | idxbuf[t];
  const int pos = atomicAdd(&start[bv], 1);
  svox[pos] = bv;
  idxbuf[t] = pos;     // idxbuf becomes spos
}

// -------- fused: pos-enc + fc_pos (60->256) + ResnetBlock 0 (64 pts) --------
__global__ __launch_bounds__(256, 4) void k_fused0(
    const float* __restrict__ p, const hf* __restrict__ fr,
    const float* __restrict__ bpos,
    const hf* __restrict__ w0f, const hf* __restrict__ w1f,
    const hf* __restrict__ wscf,
    const float* __restrict__ b0, const float* __restrict__ b1,
    const int* __restrict__ spos, hf* __restrict__ net)
{
  __shared__ __align__(16) hf swX[16384];   // 32 KB: enc (8KB) -> X frags; H aliases
  __shared__ int sp[64];
  const int tid = threadIdx.x;
  const int wv = tid >> 6, lane = tid & 63;
  const int r = lane & 15, g = lane >> 4;
  const int t0 = blockIdx.x * 64;

  if (tid < 64) sp[tid] = spos[t0 + tid];

  // Phase A: cooperative pos-enc (1920 tasks over 256 threads).
  if (tid < 64) {
    const int mt = tid >> 4, rr = tid & 15;
    *(unsigned long long*)(swX + (((mt * 2 + 1) * 64 + 48 + rr) << 3) + 4) = 0ull;
  }
#pragma unroll
  for (int i = 0; i < 8; ++i) {
    const int tau = tid + i * 256;
    if (tau >= 1920) break;
    const int pt = (int)(((unsigned)tau * 34953u) >> 20);   // tau/30
    const int a  = tau - pt * 30;
    const int fi = (a * 11) >> 5;                           // a/3
    const int comp = a - 3 * fi;
    const float pc = p[(size_t)(t0 + pt) * 3 + comp];
    const float ang = (float)(1 << fi) * 3.14159274101257324f * pc;
    const float sv = __sinf(ang), cv = __cosf(ang);
    const int mt = pt >> 4, rr = pt & 15;
    const int ks = 6 * fi + comp;
    {
      const int kc = ks >> 5, kk = ks & 31, gg = (kk >> 2) & 3;
      const int e = (kk & 3) + 4 * (kk >> 4);
      swX[(((mt * 2 + kc) * 64 + gg * 16 + rr) << 3) + e] = (hf)sv;
    }
    {
      const int kco = ks + 3;
      const int kc = kco >> 5, kk = kco & 31, gg = (kk >> 2) & 3;
      const int e = (kk & 3) + 4 * (kk >> 4);
      swX[(((mt * 2 + kc) * 64 + gg * 16 + rr) << 3) + e] = (hf)cv;
    }
  }
  __syncthreads();

  // fc_pos via MFMA, A-fragments from LDS
  f32x4 acc[4][4];
#pragma unroll
  for (int nf = 0; nf < 4; ++nf) {
    float bv = bpos[wv * 64 + nf * 16 + r];
#pragma unroll
    for (int mf = 0; mf < 4; ++mf) acc[mf][nf] = splat4(bv);
  }
#pragma unroll
  for (int kc = 0; kc < 2; ++kc) {
    hf8 a[4];
#pragma unroll
    for (int mf = 0; mf < 4; ++mf)
      a[mf] = *(const hf8*)(swX + (((mf * 2 + kc) * 64 + lane) << 3));
#pragma unroll
    for (int nf = 0; nf < 4; ++nf) {
      hf8 b = ldfrag(fr + OFF_WPOS, kc, wv * 4 + nf, 16, lane);
#pragma unroll
      for (int mf = 0; mf < 4; ++mf) acc[mf][nf] = MFMA16(a[mf], b, acc[mf][nf]);
    }
  }
  __syncthreads();   // enc region dead; X-store below overwrites it

  // X -> frag-linear LDS, swizzled slot
#pragma unroll
  for (int mf = 0; mf < 4; ++mf)
#pragma unroll
    for (int nf = 0; nf < 4; ++nf)
#pragma unroll
      for (int reg = 0; reg < 4; ++reg) {
        int rr = 4 * g + reg;
        int c  = wv * 64 + nf * 16 + r;
        int kc = c >> 5;
        int kk = c & 31;
        int gg = (kk >> 2) & 3;
        int e  = (kk & 3) + 4 * (kk >> 4);
        int slot = gg * 16 + ((rr + gg) & 15);
        swX[(((size_t)(mf * 8 + kc) * 64 + slot) << 3) + e] = (hf)acc[mf][nf][reg];
      }
  __syncthreads();

  const int wm = wv >> 1, wn = wv & 1;
  const int lidx = g * 16 + ((r + g) & 15);

  f32x4 h[2][4], d[2][4];
#pragma unroll
  for (int nf = 0; nf < 4; ++nf) {
    const int n = wn * 64 + nf * 16 + r;
    const float bh = b0[n], bd = b1[n];
#pragma unroll
    for (int mf = 0; mf < 2; ++mf) { h[mf][nf] = splat4(bh); d[mf][nf] = splat4(bd); }
  }
#pragma unroll 2
  for (int kc = 0; kc < 8; ++kc) {
    hf8 a[2], ar[2];
#pragma unroll
    for (int mf = 0; mf < 2; ++mf) {
      a[mf] = *(const hf8*)(swX + (((size_t)((wm * 2 + mf) * 8 + kc) * 64 + lidx) << 3));
      ar[mf] = relu8(a[mf]);
    }
#pragma unroll
    for (int nf = 0; nf < 4; ++nf) {
      hf8 bw0 = ldfrag(w0f, kc, wn * 4 + nf, 8, lane);
      hf8 bws = ldfrag(wscf, kc, wn * 4 + nf, 8, lane);
#pragma unroll
      for (int mf = 0; mf < 2; ++mf) {
        h[mf][nf] = MFMA16(ar[mf], bw0, h[mf][nf]);
        d[mf][nf] = MFMA16(a[mf],  bws, d[mf][nf]);
      }
    }
  }
  __syncthreads();

#pragma unroll
  for (int mf = 0; mf < 2; ++mf)
#pragma unroll
    for (int nf = 0; nf < 4; ++nf)
#pragma unroll
      for (int reg = 0; reg < 4; ++reg) {
        int m = wm * 32 + mf * 16 + 4 * g + reg;
        int k = wn * 64 + nf * 16 + r;
        float hv = fmaxf(h[mf][nf][reg], 0.f);
        int mt = m >> 4, rr = m & 15;
        int kc = k >> 5, kk = k & 31;
        int gg = (kk >> 2) & 3;
        int e = (kk & 3) + 4 * (kk >> 4);
        int slot = gg * 16 + ((rr + gg) & 15);
        swX[(((size_t)(mt * 4 + kc) * 64 + slot) << 3) + e] = (hf)hv;
      }
  __syncthreads();

#pragma unroll
  for (int kc = 0; kc < 4; ++kc) {
    hf8 a[2];
#pragma unroll
    for (int mf = 0; mf < 2; ++mf)
      a[mf] = *(const hf8*)(swX + (((size_t)((wm * 2 + mf) * 4 + kc) * 64 + lidx) << 3));
#pragma unroll
    for (int nf = 0; nf < 4; ++nf) {
      hf8 bw1 = ldfrag(w1f, kc, wn * 4 + nf, 8, lane);
#pragma unroll
      for (int mf = 0; mf < 2; ++mf) d[mf][nf] = MFMA16(a[mf], bw1, d[mf][nf]);
    }
  }

#pragma unroll
  for (int mf = 0; mf < 2; ++mf)
#pragma unroll
    for (int nf = 0; nf < 4; ++nf)
#pragma unroll
      for (int reg = 0; reg < 4; ++reg) {
        int m = wm * 32 + mf * 16 + 4 * g + reg;
        int n = wn * 64 + nf * 16 + r;
        net[(size_t)sp[m] * 128 + n] = (hf)d[mf][nf][reg];
      }
}

// ---------------- pool: streaming gather-max per voxel (16 lanes) -----------
__global__ __launch_bounds__(256) void k_pool(
    const hf* __restrict__ net, const int* __restrict__ start,
    const int* __restrict__ cnt, hf* __restrict__ fea)
{
  const int gid = blockIdx.x * 256 + threadIdx.x;
  const int bv = gid >> 4;
  const int q = gid & 15;
  const int n = cnt[bv];
  if (n == 0) return;
  const int end = start[bv], beg = end - n;
  float m[8];
#pragma unroll
  for (int e = 0; e < 8; ++e) m[e] = -1e30f;
  for (int i = beg; i < end; ++i) {
    union { uint4 u; hf h[8]; } x;
    x.u = *(const uint4*)(net + (size_t)i * 128 + 8 * q);
#pragma unroll
    for (int e = 0; e < 8; ++e) m[e] = fmaxf(m[e], (float)x.h[e]);
  }
  union { uint4 u; hf h[8]; } o;
#pragma unroll
  for (int e = 0; e < 8; ++e) o.h[e] = (hf)m[e];
  *(uint4*)(fea + ((size_t)bv << 7) + 8 * q) = o.u;
}

// ---- ResnetBlockFC for 128 sorted points, 512 threads / 8 waves ------------
// Wave (wm 0..3, wn 0..1) owns a 32x64 output slice. Same tile, same LDS,
// 2 blocks/CU -> 16 waves/CU (was 8): barrier bubbles covered.
__global__ __launch_bounds__(512, 4) void k_res(
    hf* __restrict__ net, const hf* __restrict__ fea,
    const int* __restrict__ svox,
    const hf* __restrict__ w0f, const hf* __restrict__ w1f,
    const hf* __restrict__ wscf,
    const float* __restrict__ b0, const float* __restrict__ b1)
{
  __shared__ __align__(16) hf swX[32768];   // 64 KB: X frags; H (32KB) aliases
  const int tid = threadIdx.x;
  const int wv = tid >> 6, lane = tid & 63;
  const int r = lane & 15, g = lane >> 4;
  const int wm = wv >> 1, wn = wv & 1;      // wm 0..3, wn 0..1
  const int t0 = blockIdx.x * 128;
  const int lidx = g * 16 + ((r + g) & 15);

  for (int cc = tid; cc < 4096; cc += 512) {
    const int cl = cc & 63;
    const int kc = (cc >> 6) & 7;
    const int mt = cc >> 9;
    const int rr = cl & 15, gg = cl >> 4;
    const int t = t0 + mt * 16 + rr;
    const int c1 = kc * 32 + 4 * gg;
    union { hf8 h; uint2 u2[2]; } x;
    const hf* srcp;
    if (kc < 4) {
      srcp = net + (size_t)t * 128 + c1;
    } else {
      srcp = fea + (((size_t)svox[t]) << 7) + (c1 - 128);
    }
    x.u2[0] = *(const uint2*)(srcp);
    x.u2[1] = *(const uint2*)(srcp + 16);
    const int slot = gg * 16 + ((rr + gg) & 15);
    *(hf8*)(swX + (((size_t)((cc & ~63) + slot)) << 3)) = x.h;
  }
  __syncthreads();

  f32x4 h[2][4], d[2][4];
#pragma unroll
  for (int nf = 0; nf < 4; ++nf) {
    const int n = wn * 64 + nf * 16 + r;
    const float bh = b0[n], bd = b1[n];
#pragma unroll
    for (int mf = 0; mf < 2; ++mf) { h[mf][nf] = splat4(bh); d[mf][nf] = splat4(bd); }
  }
#pragma unroll 2
  for (int kc = 0; kc < 8; ++kc) {
    hf8 a[2], ar[2];
#pragma unroll
    for (int mf = 0; mf < 2; ++mf) {
      a[mf] = *(const hf8*)(swX + (((size_t)((wm * 2 + mf) * 8 + kc) * 64 + lidx) << 3));
      ar[mf] = relu8(a[mf]);
    }
#pragma unroll
    for (int nf = 0; nf < 4; ++nf) {
      hf8 bw0 = ldfrag(w0f, kc, wn * 4 + nf, 8, lane);
      hf8 bws = ldfrag(wscf, kc, wn * 4 + nf, 8, lane);
#pragma unroll
      for (int mf = 0; mf < 2; ++mf) {
        h[mf][nf] = MFMA16(ar[mf], bw0, h[mf][nf]);
        d[mf][nf] = MFMA16(a[mf],  bws, d[mf][nf]);
      }
    }
  }
  __syncthreads();

  // H = relu(h) -> swX[0..16384), swizzled (m = wm*32 + mf*16 + 4g+reg)
#pragma unroll
  for (int mf = 0; mf < 2; ++mf)
#pragma unroll
    for (int nf = 0; nf < 4; ++nf)
#pragma unroll
      for (int reg = 0; reg < 4; ++reg) {
        int m = wm * 32 + mf * 16 + 4 * g + reg;
        int k = wn * 64 + nf * 16 + r;
        float hv = fmaxf(h[mf][nf][reg], 0.f);
        int mt = m >> 4, rr = m & 15;
        int kc = k >> 5, kk = k & 31;
        int gg = (kk >> 2) & 3;
        int e = (kk & 3) + 4 * (kk >> 4);
        int slot = gg * 16 + ((rr + gg) & 15);
        swX[(((size_t)(mt * 4 + kc) * 64 + slot) << 3) + e] = (hf)hv;
      }
  __syncthreads();

#pragma unroll
  for (int kc = 0; kc < 4; ++kc) {
    hf8 a[2];
#pragma unroll
    for (int mf = 0; mf < 2; ++mf)
      a[mf] = *(const hf8*)(swX + (((size_t)((wm * 2 + mf) * 4 + kc) * 64 + lidx) << 3));
#pragma unroll
    for (int nf = 0; nf < 4; ++nf) {
      hf8 bw1 = ldfrag(w1f, kc, wn * 4 + nf, 8, lane);
#pragma unroll
      for (int mf = 0; mf < 2; ++mf) d[mf][nf] = MFMA16(a[mf], bw1, d[mf][nf]);
    }
  }

#pragma unroll
  for (int mf = 0; mf < 2; ++mf)
#pragma unroll
    for (int nf = 0; nf < 4; ++nf)
#pragma unroll
      for (int reg = 0; reg < 4; ++reg) {
        int m = wm * 32 + mf * 16 + 4 * g + reg;
        int n = wn * 64 + nf * 16 + r;
        net[(size_t)(t0 + m) * 128 + n] = (hf)d[mf][nf][reg];
      }
}

// ---------------- fc_c via MFMA, in-place over net --------------------------
__global__ __launch_bounds__(256, 4) void k_fcc(
    hf* __restrict__ net, const hf* __restrict__ wcf, const float* __restrict__ bc)
{
  __shared__ __align__(16) hf swX[16384];
  const int tid = threadIdx.x;
  const int wv = tid >> 6, lane = tid & 63;
  const int r = lane & 15, g = lane >> 4;
  const int wm = wv >> 1, wn = wv & 1;
  const int t0 = blockIdx.x * 128;

  for (int cc = tid; cc < 2048; cc += 256) {
    const int cl = cc & 63;
    const int kc = (cc >> 6) & 3;
    const int mt = cc >> 8;
    const int rr = cl & 15, gg = cl >> 4;
    const int t = t0 + mt * 16 + rr;
    const int c1 = kc * 32 + 4 * gg;
    union { hf8 h; uint2 u2[2]; } x;
    const hf* srcp = net + (size_t)t * 128 + c1;
    x.u2[0] = *(const uint2*)(srcp);
    x.u2[1] = *(const uint2*)(srcp + 16);
    *(hf8*)(swX + ((size_t)cc << 3)) = x.h;
  }
  __syncthreads();

  f32x4 d[4][4];
#pragma unroll
  for (int nf = 0; nf < 4; ++nf) {
    float bv = bc[wn * 64 + nf * 16 + r];
#pragma unroll
    for (int mf = 0; mf < 4; ++mf) d[mf][nf] = splat4(bv);
  }
#pragma unroll
  for (int kc = 0; kc < 4; ++kc) {
    hf8 a[4];
#pragma unroll
    for (int mf = 0; mf < 4; ++mf)
      a[mf] = *(const hf8*)(swX + (((size_t)((wm * 4 + mf) * 4 + kc) * 64 + lane) << 3));
#pragma unroll
    for (int nf = 0; nf < 4; ++nf) {
      hf8 b = ldfrag(wcf, kc, wn * 4 + nf, 8, lane);
#pragma unroll
      for (int mf = 0; mf < 4; ++mf) d[mf][nf] = MFMA16(a[mf], b, d[mf][nf]);
    }
  }

#pragma unroll
  for (int mf = 0; mf < 4; ++mf)
#pragma unroll
    for (int nf = 0; nf < 4; ++nf)
#pragma unroll
      for (int reg = 0; reg < 4; ++reg) {
        int m = wm * 64 + mf * 16 + 4 * g + reg;
        int n = wn * 64 + nf * 16 + r;
        net[(size_t)(t0 + m) * 128 + n] = (hf)d[mf][nf][reg];
      }
}

// ---------------- streaming gather-mean + transpose -------------------------
__global__ __launch_bounds__(256) void k_write(
    const hf* __restrict__ cbuf, const int* __restrict__ start,
    const int* __restrict__ cnt, float* __restrict__ out)
{
  __shared__ float tile[128 * 65];
  const int tid = threadIdx.x;
  const int grp = tid >> 4, q = tid & 15;
  const int g0 = blockIdx.x * 64;        // voxel base, (b<<15)|v0
  for (int vl = grp; vl < 64; vl += 16) {
    const int bv = g0 + vl;
    const int n = cnt[bv];
    const int end = start[bv], beg = end - n;
    float s[8] = {0, 0, 0, 0, 0, 0, 0, 0};
    for (int i = beg; i < end; ++i) {
      union { uint4 u; hf h[8]; } x;
      x.u = *(const uint4*)(cbuf + (size_t)i * 128 + 8 * q);
#pragma unroll
      for (int e = 0; e < 8; ++e) s[e] += (float)x.h[e];
    }
    const float inv = 1.0f / fmaxf((float)n, 1.0f);
#pragma unroll
    for (int e = 0; e < 8; ++e) tile[(8 * q + e) * 65 + vl] = s[e] * inv;
  }
  __syncthreads();
  const int b = g0 >> 15, v0 = g0 & 32767;
  for (int i = tid; i < 8192; i += 256) {
    const int c = i >> 6, vl = i & 63;
    out[(((size_t)(b * 128 + c)) << 15) + v0 + vl] = tile[c * 65 + vl];
  }
}

extern "C" void kernel_launch(void* const* d_in, const int* in_sizes, int n_in,
                              void* d_out, int out_size, void* d_ws, size_t ws_size,
                              hipStream_t stream)
{
  const float* p    = (const float*)d_in[0];
  const float* wpos = (const float*)d_in[1];
  const float* bpos = (const float*)d_in[2];
  const float* w0   = (const float*)d_in[3];
  const float* b0   = (const float*)d_in[4];
  const float* w1   = (const float*)d_in[5];
  const float* b1   = (const float*)d_in[6];
  const float* wsc  = (const float*)d_in[7];
  const float* wc   = (const float*)d_in[8];
  const float* bc   = (const float*)d_in[9];

  char* ws = (char*)d_ws;
  int* idxbuf = (int*)ws;                           // 1 MiB (voxel ids -> spos)
  hf*  net    = (hf*)(ws + (1u << 20));             // 64 MiB (sorted rows)
  hf*  fea    = (hf*)(ws + (65u << 20));            // 32 MiB
  int* cnt32  = (int*)(ws + (97u << 20));           // 512 KiB
  int* total  = (int*)(ws + (97u << 20) + 0x80000); // 4 B
  int* startb = (int*)(ws + (97u << 20) + 0x80400); // 512 KiB
  int* svox   = (int*)(ws + (97u << 20) + 0x100400);// 1 MiB
  hf*  fr     = (hf*)d_out;  // weight frags; d_out fully overwritten by k_write

  k_prep<<<216, 256, 0, stream>>>(wpos, w0, w1, wsc, wc, fr);

  hipMemsetAsync(cnt32, 0, 0x80000 + 0x400, stream);
  k_idxcnt<<<NPTS / 256, 256, 0, stream>>>(p, idxbuf, cnt32);
  k_scan<<<NVOX / 512, 256, 0, stream>>>(cnt32, startb, total);
  k_fill<<<NPTS / 256, 256, 0, stream>>>(idxbuf, startb, svox);

  k_fused0<<<NPTS / 64, 256, 0, stream>>>(p, fr, bpos,
      fr + OFF_W0, fr + OFF_W1, fr + OFF_WSC, b0, b1, idxbuf, net);

  for (int i = 1; i < 5; ++i) {
    k_pool<<<(NVOX * 16) / 256, 256, 0, stream>>>(net, startb, cnt32, fea);
    k_res<<<NPTS / 128, 512, 0, stream>>>(net, fea, svox,
        fr + OFF_W0 + (size_t)i * 32768, fr + OFF_W1 + (size_t)i * 16384,
        fr + OFF_WSC + (size_t)i * 32768, b0 + i * 128, b1 + i * 128);
  }

  k_fcc<<<NPTS / 128, 256, 0, stream>>>(net, fr + OFF_WC, bc);
  k_write<<<NVOX / 64, 256, 0, stream>>>(net, startb, cnt32, (float*)d_out);
}

// Round 8
// 619.192 us; speedup vs baseline: 1.0848x; 1.0848x over previous
//
#include <hip/hip_runtime.h>

typedef _Float16 hf;
typedef _Float16 hf8 __attribute__((ext_vector_type(8)));
typedef float f32x4 __attribute__((ext_vector_type(4)));

static constexpr int BATCH = 4;
static constexpr int TPTS  = 65536;
static constexpr int NPTS  = BATCH * TPTS;   // 262144
static constexpr int R3    = 32768;
static constexpr int NVOX  = BATCH * R3;     // 131072

// fragment-linear f16 weight buffers (units of hf) inside d_out scratch.
static constexpr int OFF_WPOS = 0;         // K=64(pad 60), N=256: 2048 chunks
static constexpr int OFF_W0   = 16384;     // 5 x (K=256,N=128)
static constexpr int OFF_W1   = 180224;    // 5 x (K=128,N=128)
static constexpr int OFF_WSC  = 262144;    // 5 x (K=256,N=128)
static constexpr int OFF_WC   = 425984;    // K=128,N=128
static constexpr int NCHUNKS  = 55296;

__device__ constexpr int kpat(int g, int j) { return (j & 3) + 4 * g + 16 * (j >> 2); }

#define MFMA16(a, b, c) __builtin_amdgcn_mfma_f32_16x16x32_f16((a), (b), (c), 0, 0, 0)

__device__ inline hf8 relu8(hf8 a) {
#pragma unroll
  for (int i = 0; i < 8; ++i) a[i] = (a[i] > (hf)0) ? a[i] : (hf)0;
  return a;
}
__device__ inline f32x4 splat4(float v) {
  f32x4 r; r[0] = v; r[1] = v; r[2] = v; r[3] = v; return r;
}
__device__ inline hf8 ldfrag(const hf* __restrict__ base, int kc, int nt, int NT, int lane) {
  return *(const hf8*)(base + (((size_t)(kc * NT + nt) * 64 + lane) << 3));
}

// ---------------- weight fragment prep --------------------------------------
__global__ __launch_bounds__(256) void k_prep(
    const float* __restrict__ wpos, const float* __restrict__ w0,
    const float* __restrict__ w1,  const float* __restrict__ wsc,
    const float* __restrict__ wc,  hf* __restrict__ fr)
{
  const int cid = blockIdx.x * 256 + threadIdx.x;
  if (cid >= NCHUNKS) return;
  const float* src; hf* dst; int NT, N, kmax, loc;
  if (cid < 2048) {
    src = wpos; dst = fr + OFF_WPOS; NT = 16; N = 256; kmax = 60; loc = cid;
  } else if (cid < 22528) {
    int l5 = cid - 2048; int i = l5 >> 12; loc = l5 & 4095;
    src = w0 + (size_t)i * 32768; dst = fr + OFF_W0 + (size_t)i * 32768;
    NT = 8; N = 128; kmax = 256;
  } else if (cid < 32768) {
    int l5 = cid - 22528; int i = l5 >> 11; loc = l5 & 2047;
    src = w1 + (size_t)i * 16384; dst = fr + OFF_W1 + (size_t)i * 16384;
    NT = 8; N = 128; kmax = 128;
  } else if (cid < 53248) {
    int l5 = cid - 32768; int i = l5 >> 12; loc = l5 & 4095;
    src = wsc + (size_t)i * 32768; dst = fr + OFF_WSC + (size_t)i * 32768;
    NT = 8; N = 128; kmax = 256;
  } else {
    loc = cid - 53248; src = wc; dst = fr + OFF_WC; NT = 8; N = 128; kmax = 128;
  }
  const int lane = loc & 63;
  const int rest = loc >> 6;
  const int nt = rest % NT, kc = rest / NT;
  const int g = lane >> 4;
  const int n = nt * 16 + (lane & 15);
  union { hf8 h; hf f[8]; } o;
#pragma unroll
  for (int j = 0; j < 8; ++j) {
    int k = kc * 32 + kpat(g, j);
    o.f[j] = (k < kmax) ? (hf)src[(size_t)k * N + n] : (hf)0;
  }
  *(hf8*)(dst + ((size_t)loc << 3)) = o.h;
}

// ---------------- voxel index + count (fused) --------------------------------
__global__ __launch_bounds__(256) void k_idxcnt(
    const float* __restrict__ p, int* __restrict__ idxbuf, int* __restrict__ cnt)
{
  const int t = blockIdx.x * 256 + threadIdx.x;
  const float px = p[(size_t)t * 3 + 0];
  const float py = p[(size_t)t * 3 + 1];
  const float pz = p[(size_t)t * 3 + 2];
  float nx = fminf(fmaxf(px / 1.101f + 0.5f, 0.0f), 0.999f);
  float ny = fminf(fmaxf(py / 1.101f + 0.5f, 0.0f), 0.999f);
  float nz = fminf(fmaxf(pz / 1.101f + 0.5f, 0.0f), 0.999f);
  const int iv = (int)(nx * 32.f) + 32 * (int)(ny * 32.f) + 1024 * (int)(nz * 32.f);
  idxbuf[t] = iv;
  atomicAdd(&cnt[((t >> 16) << 15) | iv], 1);
}

__global__ __launch_bounds__(256) void k_scan(
    const int* __restrict__ cnt, int* __restrict__ start, int* __restrict__ total)
{
  __shared__ int s[256];
  __shared__ int base_s;
  const int tid = threadIdx.x;
  const int v0 = blockIdx.x * 512;
  const int a = cnt[v0 + 2 * tid], b = cnt[v0 + 2 * tid + 1];
  const int sum = a + b;
  s[tid] = sum;
  __syncthreads();
  for (int off = 1; off < 256; off <<= 1) {
    int x = (tid >= off) ? s[tid - off] : 0;
    __syncthreads();
    s[tid] += x;
    __syncthreads();
  }
  if (tid == 255) base_s = atomicAdd(total, s[255]);
  __syncthreads();
  const int excl = base_s + s[tid] - sum;
  start[v0 + 2 * tid]     = excl;
  start[v0 + 2 * tid + 1] = excl + a;
}

// fill: advance start[bv] to END; record sorted slot (spos, in-place over
// idxbuf) and voxel per sorted slot (svox).
__global__ __launch_bounds__(256) void k_fill(
    int* __restrict__ idxbuf, int* __restrict__ start, int* __restrict__ svox)
{
  const int t = blockIdx.x * 256 + threadIdx.x;
  const int bv = ((t >> 16) << 15) | idxbuf[t];
  const int pos = atomicAdd(&start[bv], 1);
  svox[pos] = bv;
  idxbuf[t] = pos;     // idxbuf becomes spos
}

// -------- fused: pos-enc + fc_pos (60->256) + ResnetBlock 0 (64 pts) --------
__global__ __launch_bounds__(256, 4) void k_fused0(
    const float* __restrict__ p, const hf* __restrict__ fr,
    const float* __restrict__ bpos,
    const hf* __restrict__ w0f, const hf* __restrict__ w1f,
    const hf* __restrict__ wscf,
    const float* __restrict__ b0, const float* __restrict__ b1,
    const int* __restrict__ spos, hf* __restrict__ net)
{
  __shared__ __align__(16) hf swX[16384];   // 32 KB: enc (8KB) -> X frags; H aliases
  __shared__ int sp[64];
  const int tid = threadIdx.x;
  const int wv = tid >> 6, lane = tid & 63;
  const int r = lane & 15, g = lane >> 4;
  const int t0 = blockIdx.x * 64;

  if (tid < 64) sp[tid] = spos[t0 + tid];

  // Phase A: cooperative pos-enc (1920 tasks over 256 threads).
  if (tid < 64) {
    const int mt = tid >> 4, rr = tid & 15;
    *(unsigned long long*)(swX + (((mt * 2 + 1) * 64 + 48 + rr) << 3) + 4) = 0ull;
  }
#pragma unroll
  for (int i = 0; i < 8; ++i) {
    const int tau = tid + i * 256;
    if (tau >= 1920) break;
    const int pt = (int)(((unsigned)tau * 34953u) >> 20);   // tau/30
    const int a  = tau - pt * 30;
    const int fi = (a * 11) >> 5;                           // a/3
    const int comp = a - 3 * fi;
    const float pc = p[(size_t)(t0 + pt) * 3 + comp];
    const float ang = (float)(1 << fi) * 3.14159274101257324f * pc;
    const float sv = __sinf(ang), cv = __cosf(ang);
    const int mt = pt >> 4, rr = pt & 15;
    const int ks = 6 * fi + comp;
    {
      const int kc = ks >> 5, kk = ks & 31, gg = (kk >> 2) & 3;
      const int e = (kk & 3) + 4 * (kk >> 4);
      swX[(((mt * 2 + kc) * 64 + gg * 16 + rr) << 3) + e] = (hf)sv;
    }
    {
      const int kco = ks + 3;
      const int kc = kco >> 5, kk = kco & 31, gg = (kk >> 2) & 3;
      const int e = (kk & 3) + 4 * (kk >> 4);
      swX[(((mt * 2 + kc) * 64 + gg * 16 + rr) << 3) + e] = (hf)cv;
    }
  }
  __syncthreads();

  // fc_pos via MFMA, A-fragments from LDS
  f32x4 acc[4][4];
#pragma unroll
  for (int nf = 0; nf < 4; ++nf) {
    float bv = bpos[wv * 64 + nf * 16 + r];
#pragma unroll
    for (int mf = 0; mf < 4; ++mf) acc[mf][nf] = splat4(bv);
  }
#pragma unroll
  for (int kc = 0; kc < 2; ++kc) {
    hf8 a[4];
#pragma unroll
    for (int mf = 0; mf < 4; ++mf)
      a[mf] = *(const hf8*)(swX + (((mf * 2 + kc) * 64 + lane) << 3));
#pragma unroll
    for (int nf = 0; nf < 4; ++nf) {
      hf8 b = ldfrag(fr + OFF_WPOS, kc, wv * 4 + nf, 16, lane);
#pragma unroll
      for (int mf = 0; mf < 4; ++mf) acc[mf][nf] = MFMA16(a[mf], b, acc[mf][nf]);
    }
  }
  __syncthreads();   // enc region dead; X-store below overwrites it

  // X -> frag-linear LDS, swizzled slot
#pragma unroll
  for (int mf = 0; mf < 4; ++mf)
#pragma unroll
    for (int nf = 0; nf < 4; ++nf)
#pragma unroll
      for (int reg = 0; reg < 4; ++reg) {
        int rr = 4 * g + reg;
        int c  = wv * 64 + nf * 16 + r;
        int kc = c >> 5;
        int kk = c & 31;
        int gg = (kk >> 2) & 3;
        int e  = (kk & 3) + 4 * (kk >> 4);
        int slot = gg * 16 + ((rr + gg) & 15);
        swX[(((size_t)(mf * 8 + kc) * 64 + slot) << 3) + e] = (hf)acc[mf][nf][reg];
      }
  __syncthreads();

  const int wm = wv >> 1, wn = wv & 1;
  const int lidx = g * 16 + ((r + g) & 15);

  f32x4 h[2][4], d[2][4];
#pragma unroll
  for (int nf = 0; nf < 4; ++nf) {
    const int n = wn * 64 + nf * 16 + r;
    const float bh = b0[n], bd = b1[n];
#pragma unroll
    for (int mf = 0; mf < 2; ++mf) { h[mf][nf] = splat4(bh); d[mf][nf] = splat4(bd); }
  }
#pragma unroll 2
  for (int kc = 0; kc < 8; ++kc) {
    hf8 a[2], ar[2];
#pragma unroll
    for (int mf = 0; mf < 2; ++mf) {
      a[mf] = *(const hf8*)(swX + (((size_t)((wm * 2 + mf) * 8 + kc) * 64 + lidx) << 3));
      ar[mf] = relu8(a[mf]);
    }
#pragma unroll
    for (int nf = 0; nf < 4; ++nf) {
      hf8 bw0 = ldfrag(w0f, kc, wn * 4 + nf, 8, lane);
      hf8 bws = ldfrag(wscf, kc, wn * 4 + nf, 8, lane);
#pragma unroll
      for (int mf = 0; mf < 2; ++mf) {
        h[mf][nf] = MFMA16(ar[mf], bw0, h[mf][nf]);
        d[mf][nf] = MFMA16(a[mf],  bws, d[mf][nf]);
      }
    }
  }
  __syncthreads();

#pragma unroll
  for (int mf = 0; mf < 2; ++mf)
#pragma unroll
    for (int nf = 0; nf < 4; ++nf)
#pragma unroll
      for (int reg = 0; reg < 4; ++reg) {
        int m = wm * 32 + mf * 16 + 4 * g + reg;
        int k = wn * 64 + nf * 16 + r;
        float hv = fmaxf(h[mf][nf][reg], 0.f);
        int mt = m >> 4, rr = m & 15;
        int kc = k >> 5, kk = k & 31;
        int gg = (kk >> 2) & 3;
        int e = (kk & 3) + 4 * (kk >> 4);
        int slot = gg * 16 + ((rr + gg) & 15);
        swX[(((size_t)(mt * 4 + kc) * 64 + slot) << 3) + e] = (hf)hv;
      }
  __syncthreads();

#pragma unroll
  for (int kc = 0; kc < 4; ++kc) {
    hf8 a[2];
#pragma unroll
    for (int mf = 0; mf < 2; ++mf)
      a[mf] = *(const hf8*)(swX + (((size_t)((wm * 2 + mf) * 4 + kc) * 64 + lidx) << 3));
#pragma unroll
    for (int nf = 0; nf < 4; ++nf) {
      hf8 bw1 = ldfrag(w1f, kc, wn * 4 + nf, 8, lane);
#pragma unroll
      for (int mf = 0; mf < 2; ++mf) d[mf][nf] = MFMA16(a[mf], bw1, d[mf][nf]);
    }
  }

#pragma unroll
  for (int mf = 0; mf < 2; ++mf)
#pragma unroll
    for (int nf = 0; nf < 4; ++nf)
#pragma unroll
      for (int reg = 0; reg < 4; ++reg) {
        int m = wm * 32 + mf * 16 + 4 * g + reg;
        int n = wn * 64 + nf * 16 + r;
        net[(size_t)sp[m] * 128 + n] = (hf)d[mf][nf][reg];
      }
}

// ---------------- pool: streaming segmented max over sorted rows ------------
// 16-lane group scans an 8-row sub-range; the group holding a segment's FIRST
// row walks the whole segment (crossing range/block ends: duplicate reads
// only) and writes the voxel's fea row exactly once. No atomics, no cnt.
__global__ __launch_bounds__(256) void k_pool(
    const hf* __restrict__ net, const int* __restrict__ svox,
    hf* __restrict__ fea)
{
  const int tid = threadIdx.x;
  const int grp = tid >> 4, q = tid & 15;
  const int gbeg = blockIdx.x * 128 + grp * 8;
  const int gend = gbeg + 8;
  int i = gbeg;
  while (i < gend) {
    const int v = svox[i];
    if (i != 0 && svox[i - 1] == v) { ++i; continue; }  // started earlier
    float m[8];
#pragma unroll
    for (int e = 0; e < 8; ++e) m[e] = -1e30f;
    int j = i;
    do {
      union { uint4 u; hf h[8]; } x;
      x.u = *(const uint4*)(net + (size_t)j * 128 + 8 * q);
#pragma unroll
      for (int e = 0; e < 8; ++e) m[e] = fmaxf(m[e], (float)x.h[e]);
      ++j;
    } while (j < NPTS && svox[j] == v);
    union { uint4 u; hf h[8]; } o;
#pragma unroll
    for (int e = 0; e < 8; ++e) o.h[e] = (hf)m[e];
    *(uint4*)(fea + ((size_t)v << 7) + 8 * q) = o.u;
    i = j;
  }
}

// ---- ResnetBlockFC for 128 sorted points via MFMA (64KB LDS). --------------
// LAST=1: fc_c fused at the tail (resblock out -> LDS -> fc_c -> net).
template <int LAST>
__global__ __launch_bounds__(256, 2) void k_res(
    hf* __restrict__ net, const hf* __restrict__ fea,
    const int* __restrict__ svox,
    const hf* __restrict__ w0f, const hf* __restrict__ w1f,
    const hf* __restrict__ wscf,
    const float* __restrict__ b0, const float* __restrict__ b1,
    const hf* __restrict__ wcf, const float* __restrict__ bc)
{
  __shared__ __align__(16) hf swX[32768];   // 64 KB: X frags; H (32KB) aliases
  const int tid = threadIdx.x;
  const int wv = tid >> 6, lane = tid & 63;
  const int r = lane & 15, g = lane >> 4;
  const int wm = wv >> 1, wn = wv & 1;
  const int t0 = blockIdx.x * 128;
  const int lidx = g * 16 + ((r + g) & 15);

  for (int cc = tid; cc < 4096; cc += 256) {
    const int cl = cc & 63;
    const int kc = (cc >> 6) & 7;
    const int mt = cc >> 9;
    const int rr = cl & 15, gg = cl >> 4;
    const int t = t0 + mt * 16 + rr;
    const int c1 = kc * 32 + 4 * gg;
    union { hf8 h; uint2 u2[2]; } x;
    const hf* srcp;
    if (kc < 4) {
      srcp = net + (size_t)t * 128 + c1;
    } else {
      srcp = fea + (((size_t)svox[t]) << 7) + (c1 - 128);
    }
    x.u2[0] = *(const uint2*)(srcp);
    x.u2[1] = *(const uint2*)(srcp + 16);
    const int slot = gg * 16 + ((rr + gg) & 15);
    *(hf8*)(swX + (((size_t)((cc & ~63) + slot)) << 3)) = x.h;
  }
  __syncthreads();

  f32x4 h[4][4], d[4][4];
#pragma unroll
  for (int nf = 0; nf < 4; ++nf) {
    const int n = wn * 64 + nf * 16 + r;
    const float bh = b0[n], bd = b1[n];
#pragma unroll
    for (int mf = 0; mf < 4; ++mf) { h[mf][nf] = splat4(bh); d[mf][nf] = splat4(bd); }
  }
#pragma unroll 2
  for (int kc = 0; kc < 8; ++kc) {
    hf8 a[4], ar[4];
#pragma unroll
    for (int mf = 0; mf < 4; ++mf) {
      a[mf] = *(const hf8*)(swX + (((size_t)((wm * 4 + mf) * 8 + kc) * 64 + lidx) << 3));
      ar[mf] = relu8(a[mf]);
    }
#pragma unroll
    for (int nf = 0; nf < 4; ++nf) {
      hf8 bw0 = ldfrag(w0f, kc, wn * 4 + nf, 8, lane);
      hf8 bws = ldfrag(wscf, kc, wn * 4 + nf, 8, lane);
#pragma unroll
      for (int mf = 0; mf < 4; ++mf) {
        h[mf][nf] = MFMA16(ar[mf], bw0, h[mf][nf]);
        d[mf][nf] = MFMA16(a[mf],  bws, d[mf][nf]);
      }
    }
  }
  __syncthreads();

  // H = relu(h) -> swX[0..16384), swizzled
#pragma unroll
  for (int mf = 0; mf < 4; ++mf)
#pragma unroll
    for (int nf = 0; nf < 4; ++nf)
#pragma unroll
      for (int reg = 0; reg < 4; ++reg) {
        int m = wm * 64 + mf * 16 + 4 * g + reg;
        int k = wn * 64 + nf * 16 + r;
        float hv = fmaxf(h[mf][nf][reg], 0.f);
        int mt = m >> 4, rr = m & 15;
        int kc = k >> 5, kk = k & 31;
        int gg = (kk >> 2) & 3;
        int e = (kk & 3) + 4 * (kk >> 4);
        int slot = gg * 16 + ((rr + gg) & 15);
        swX[(((size_t)(mt * 4 + kc) * 64 + slot) << 3) + e] = (hf)hv;
      }
  __syncthreads();

#pragma unroll
  for (int kc = 0; kc < 4; ++kc) {
    hf8 a[4];
#pragma unroll
    for (int mf = 0; mf < 4; ++mf)
      a[mf] = *(const hf8*)(swX + (((size_t)((wm * 4 + mf) * 4 + kc) * 64 + lidx) << 3));
#pragma unroll
    for (int nf = 0; nf < 4; ++nf) {
      hf8 bw1 = ldfrag(w1f, kc, wn * 4 + nf, 8, lane);
#pragma unroll
      for (int mf = 0; mf < 4; ++mf) d[mf][nf] = MFMA16(a[mf], bw1, d[mf][nf]);
    }
  }

  if (LAST) {
    // resblock out (d) -> LDS (f16, same rounding point as the old global
    // round-trip), then fc_c: c = d @ wc + bc, written to net.
    __syncthreads();
#pragma unroll
    for (int mf = 0; mf < 4; ++mf)
#pragma unroll
      for (int nf = 0; nf < 4; ++nf)
#pragma unroll
        for (int reg = 0; reg < 4; ++reg) {
          int m = wm * 64 + mf * 16 + 4 * g + reg;
          int k = wn * 64 + nf * 16 + r;
          int mt = m >> 4, rr = m & 15;
          int kc = k >> 5, kk = k & 31;
          int gg = (kk >> 2) & 3;
          int e = (kk & 3) + 4 * (kk >> 4);
          int slot = gg * 16 + ((rr + gg) & 15);
          swX[(((size_t)(mt * 4 + kc) * 64 + slot) << 3) + e] = (hf)d[mf][nf][reg];
        }
    __syncthreads();

    f32x4 c2[4][4];
#pragma unroll
    for (int nf = 0; nf < 4; ++nf) {
      float bv = bc[wn * 64 + nf * 16 + r];
#pragma unroll
      for (int mf = 0; mf < 4; ++mf) c2[mf][nf] = splat4(bv);
    }
#pragma unroll
    for (int kc = 0; kc < 4; ++kc) {
      hf8 a[4];
#pragma unroll
      for (int mf = 0; mf < 4; ++mf)
        a[mf] = *(const hf8*)(swX + (((size_t)((wm * 4 + mf) * 4 + kc) * 64 + lidx) << 3));
#pragma unroll
      for (int nf = 0; nf < 4; ++nf) {
        hf8 bw = ldfrag(wcf, kc, wn * 4 + nf, 8, lane);
#pragma unroll
        for (int mf = 0; mf < 4; ++mf) c2[mf][nf] = MFMA16(a[mf], bw, c2[mf][nf]);
      }
    }
#pragma unroll
    for (int mf = 0; mf < 4; ++mf)
#pragma unroll
      for (int nf = 0; nf < 4; ++nf)
#pragma unroll
        for (int reg = 0; reg < 4; ++reg) {
          int m = wm * 64 + mf * 16 + 4 * g + reg;
          int n = wn * 64 + nf * 16 + r;
          net[(size_t)(t0 + m) * 128 + n] = (hf)c2[mf][nf][reg];
        }
  } else {
#pragma unroll
    for (int mf = 0; mf < 4; ++mf)
#pragma unroll
      for (int nf = 0; nf < 4; ++nf)
#pragma unroll
        for (int reg = 0; reg < 4; ++reg) {
          int m = wm * 64 + mf * 16 + 4 * g + reg;
          int n = wn * 64 + nf * 16 + r;
          net[(size_t)(t0 + m) * 128 + n] = (hf)d[mf][nf][reg];
        }
  }
}

// ---------------- streaming gather-mean + transpose -------------------------
__global__ __launch_bounds__(256) void k_write(
    const hf* __restrict__ cbuf, const int* __restrict__ start,
    const int* __restrict__ cnt, float* __restrict__ out)
{
  __shared__ float tile[128 * 65];
  const int tid = threadIdx.x;
  const int grp = tid >> 4, q = tid & 15;
  const int g0 = blockIdx.x * 64;        // voxel base, (b<<15)|v0
  for (int vl = grp; vl < 64; vl += 16) {
    const int bv = g0 + vl;
    const int n = cnt[bv];
    const int end = start[bv], beg = end - n;
    float s[8] = {0, 0, 0, 0, 0, 0, 0, 0};
    for (int i = beg; i < end; ++i) {
      union { uint4 u; hf h[8]; } x;
      x.u = *(const uint4*)(cbuf + (size_t)i * 128 + 8 * q);
#pragma unroll
      for (int e = 0; e < 8; ++e) s[e] += (float)x.h[e];
    }
    const float inv = 1.0f / fmaxf((float)n, 1.0f);
#pragma unroll
    for (int e = 0; e < 8; ++e) tile[(8 * q + e) * 65 + vl] = s[e] * inv;
  }
  __syncthreads();
  const int b = g0 >> 15, v0 = g0 & 32767;
  for (int i = tid; i < 8192; i += 256) {
    const int c = i >> 6, vl = i & 63;
    out[(((size_t)(b * 128 + c)) << 15) + v0 + vl] = tile[c * 65 + vl];
  }
}

extern "C" void kernel_launch(void* const* d_in, const int* in_sizes, int n_in,
                              void* d_out, int out_size, void* d_ws, size_t ws_size,
                              hipStream_t stream)
{
  const float* p    = (const float*)d_in[0];
  const float* wpos = (const float*)d_in[1];
  const float* bpos = (const float*)d_in[2];
  const float* w0   = (const float*)d_in[3];
  const float* b0   = (const float*)d_in[4];
  const float* w1   = (const float*)d_in[5];
  const float* b1   = (const float*)d_in[6];
  const float* wsc  = (const float*)d_in[7];
  const float* wc   = (const float*)d_in[8];
  const float* bc   = (const float*)d_in[9];

  char* ws = (char*)d_ws;
  int* idxbuf = (int*)ws;                           // 1 MiB (voxel ids -> spos)
  hf*  net    = (hf*)(ws + (1u << 20));             // 64 MiB (sorted rows)
  hf*  fea    = (hf*)(ws + (65u << 20));            // 32 MiB
  int* cnt32  = (int*)(ws + (97u << 20));           // 512 KiB
  int* total  = (int*)(ws + (97u << 20) + 0x80000); // 4 B
  int* startb = (int*)(ws + (97u << 20) + 0x80400); // 512 KiB
  int* svox   = (int*)(ws + (97u << 20) + 0x100400);// 1 MiB
  hf*  fr     = (hf*)d_out;  // weight frags; d_out fully overwritten by k_write

  k_prep<<<216, 256, 0, stream>>>(wpos, w0, w1, wsc, wc, fr);

  hipMemsetAsync(cnt32, 0, 0x80000 + 0x400, stream);
  k_idxcnt<<<NPTS / 256, 256, 0, stream>>>(p, idxbuf, cnt32);
  k_scan<<<NVOX / 512, 256, 0, stream>>>(cnt32, startb, total);
  k_fill<<<NPTS / 256, 256, 0, stream>>>(idxbuf, startb, svox);

  k_fused0<<<NPTS / 64, 256, 0, stream>>>(p, fr, bpos,
      fr + OFF_W0, fr + OFF_W1, fr + OFF_WSC, b0, b1, idxbuf, net);

  for (int i = 1; i < 4; ++i) {
    k_pool<<<NPTS / 128, 256, 0, stream>>>(net, svox, fea);
    k_res<0><<<NPTS / 128, 256, 0, stream>>>(net, fea, svox,
        fr + OFF_W0 + (size_t)i * 32768, fr + OFF_W1 + (size_t)i * 16384,
        fr + OFF_WSC + (size_t)i * 32768, b0 + i * 128, b1 + i * 128,
        nullptr, nullptr);
  }
  k_pool<<<NPTS / 128, 256, 0, stream>>>(net, svox, fea);
  k_res<1><<<NPTS / 128, 256, 0, stream>>>(net, fea, svox,
      fr + OFF_W0 + (size_t)4 * 32768, fr + OFF_W1 + (size_t)4 * 16384,
      fr + OFF_WSC + (size_t)4 * 32768, b0 + 4 * 128, b1 + 4 * 128,
      fr + OFF_WC, bc);

  k_write<<<NVOX / 64, 256, 0, stream>>>(net, startb, cnt32, (float*)d_out);
}

// Round 9
// 566.425 us; speedup vs baseline: 1.1858x; 1.0932x over previous
//
#include <hip/hip_runtime.h>

typedef _Float16 hf;
typedef _Float16 hf8 __attribute__((ext_vector_type(8)));
typedef float f32x4 __attribute__((ext_vector_type(4)));

static constexpr int BATCH = 4;
static constexpr int TPTS  = 65536;
static constexpr int NPTS  = BATCH * TPTS;   // 262144
static constexpr int R3    = 32768;
static constexpr int NVOX  = BATCH * R3;     // 131072

// fragment-linear f16 weight buffers (units of hf) inside d_out scratch.
static constexpr int OFF_WPOS = 0;         // K=64(pad 60), N=256: 2048 chunks
static constexpr int OFF_W0   = 16384;     // 5 x (K=256,N=128)
static constexpr int OFF_W1   = 180224;    // 5 x (K=128,N=128)
static constexpr int OFF_WSC  = 262144;    // 5 x (K=256,N=128)
static constexpr int OFF_WC   = 425984;    // K=128,N=128
static constexpr int NCHUNKS  = 55296;

__device__ constexpr int kpat(int g, int j) { return (j & 3) + 4 * g + 16 * (j >> 2); }

#define MFMA16(a, b, c) __builtin_amdgcn_mfma_f32_16x16x32_f16((a), (b), (c), 0, 0, 0)

__device__ inline hf8 relu8(hf8 a) {
#pragma unroll
  for (int i = 0; i < 8; ++i) a[i] = (a[i] > (hf)0) ? a[i] : (hf)0;
  return a;
}
__device__ inline f32x4 splat4(float v) {
  f32x4 r; r[0] = v; r[1] = v; r[2] = v; r[3] = v; return r;
}
__device__ inline hf8 ldfrag(const hf* __restrict__ base, int kc, int nt, int NT, int lane) {
  return *(const hf8*)(base + (((size_t)(kc * NT + nt) * 64 + lane) << 3));
}

// ---------------- weight fragment prep --------------------------------------
__global__ __launch_bounds__(256) void k_prep(
    const float* __restrict__ wpos, const float* __restrict__ w0,
    const float* __restrict__ w1,  const float* __restrict__ wsc,
    const float* __restrict__ wc,  hf* __restrict__ fr)
{
  const int cid = blockIdx.x * 256 + threadIdx.x;
  if (cid >= NCHUNKS) return;
  const float* src; hf* dst; int NT, N, kmax, loc;
  if (cid < 2048) {
    src = wpos; dst = fr + OFF_WPOS; NT = 16; N = 256; kmax = 60; loc = cid;
  } else if (cid < 22528) {
    int l5 = cid - 2048; int i = l5 >> 12; loc = l5 & 4095;
    src = w0 + (size_t)i * 32768; dst = fr + OFF_W0 + (size_t)i * 32768;
    NT = 8; N = 128; kmax = 256;
  } else if (cid < 32768) {
    int l5 = cid - 22528; int i = l5 >> 11; loc = l5 & 2047;
    src = w1 + (size_t)i * 16384; dst = fr + OFF_W1 + (size_t)i * 16384;
    NT = 8; N = 128; kmax = 128;
  } else if (cid < 53248) {
    int l5 = cid - 32768; int i = l5 >> 12; loc = l5 & 4095;
    src = wsc + (size_t)i * 32768; dst = fr + OFF_WSC + (size_t)i * 32768;
    NT = 8; N = 128; kmax = 256;
  } else {
    loc = cid - 53248; src = wc; dst = fr + OFF_WC; NT = 8; N = 128; kmax = 128;
  }
  const int lane = loc & 63;
  const int rest = loc >> 6;
  const int nt = rest % NT, kc = rest / NT;
  const int g = lane >> 4;
  const int n = nt * 16 + (lane & 15);
  union { hf8 h; hf f[8]; } o;
#pragma unroll
  for (int j = 0; j < 8; ++j) {
    int k = kc * 32 + kpat(g, j);
    o.f[j] = (k < kmax) ? (hf)src[(size_t)k * N + n] : (hf)0;
  }
  *(hf8*)(dst + ((size_t)loc << 3)) = o.h;
}

// ---------------- voxel index + count (fused) --------------------------------
__global__ __launch_bounds__(256) void k_idxcnt(
    const float* __restrict__ p, int* __restrict__ idxbuf, int* __restrict__ cnt)
{
  const int t = blockIdx.x * 256 + threadIdx.x;
  const float px = p[(size_t)t * 3 + 0];
  const float py = p[(size_t)t * 3 + 1];
  const float pz = p[(size_t)t * 3 + 2];
  float nx = fminf(fmaxf(px / 1.101f + 0.5f, 0.0f), 0.999f);
  float ny = fminf(fmaxf(py / 1.101f + 0.5f, 0.0f), 0.999f);
  float nz = fminf(fmaxf(pz / 1.101f + 0.5f, 0.0f), 0.999f);
  const int iv = (int)(nx * 32.f) + 32 * (int)(ny * 32.f) + 1024 * (int)(nz * 32.f);
  idxbuf[t] = iv;
  atomicAdd(&cnt[((t >> 16) << 15) | iv], 1);
}

__global__ __launch_bounds__(256) void k_scan(
    const int* __restrict__ cnt, int* __restrict__ start, int* __restrict__ total)
{
  __shared__ int s[256];
  __shared__ int base_s;
  const int tid = threadIdx.x;
  const int v0 = blockIdx.x * 512;
  const int a = cnt[v0 + 2 * tid], b = cnt[v0 + 2 * tid + 1];
  const int sum = a + b;
  s[tid] = sum;
  __syncthreads();
  for (int off = 1; off < 256; off <<= 1) {
    int x = (tid >= off) ? s[tid - off] : 0;
    __syncthreads();
    s[tid] += x;
    __syncthreads();
  }
  if (tid == 255) base_s = atomicAdd(total, s[255]);
  __syncthreads();
  const int excl = base_s + s[tid] - sum;
  start[v0 + 2 * tid]     = excl;
  start[v0 + 2 * tid + 1] = excl + a;
}

// fill: advance start[bv] to END; record sorted slot (spos, in-place over
// idxbuf) and voxel per sorted slot (svox).
__global__ __launch_bounds__(256) void k_fill(
    int* __restrict__ idxbuf, int* __restrict__ start, int* __restrict__ svox)
{
  const int t = blockIdx.x * 256 + threadIdx.x;
  const int bv = ((t >> 16) << 15) | idxbuf[t];
  const int pos = atomicAdd(&start[bv], 1);
  svox[pos] = bv;
  idxbuf[t] = pos;     // idxbuf becomes spos
}

// -------- fused: pos-enc + fc_pos (60->256) + ResnetBlock 0 (64 pts) --------
__global__ __launch_bounds__(256, 4) void k_fused0(
    const float* __restrict__ p, const hf* __restrict__ fr,
    const float* __restrict__ bpos,
    const hf* __restrict__ w0f, const hf* __restrict__ w1f,
    const hf* __restrict__ wscf,
    const float* __restrict__ b0, const float* __restrict__ b1,
    const int* __restrict__ spos, hf* __restrict__ net)
{
  __shared__ __align__(16) hf swX[16384];   // 32 KB: enc (8KB) -> X frags; H aliases
  __shared__ int sp[64];
  const int tid = threadIdx.x;
  const int wv = tid >> 6, lane = tid & 63;
  const int r = lane & 15, g = lane >> 4;
  const int t0 = blockIdx.x * 64;

  if (tid < 64) sp[tid] = spos[t0 + tid];

  // Phase A: cooperative pos-enc (1920 tasks over 256 threads).
  if (tid < 64) {
    const int mt = tid >> 4, rr = tid & 15;
    *(unsigned long long*)(swX + (((mt * 2 + 1) * 64 + 48 + rr) << 3) + 4) = 0ull;
  }
#pragma unroll
  for (int i = 0; i < 8; ++i) {
    const int tau = tid + i * 256;
    if (tau >= 1920) break;
    const int pt = (int)(((unsigned)tau * 34953u) >> 20);   // tau/30
    const int a  = tau - pt * 30;
    const int fi = (a * 11) >> 5;                           // a/3
    const int comp = a - 3 * fi;
    const float pc = p[(size_t)(t0 + pt) * 3 + comp];
    const float ang = (float)(1 << fi) * 3.14159274101257324f * pc;
    const float sv = __sinf(ang), cv = __cosf(ang);
    const int mt = pt >> 4, rr = pt & 15;
    const int ks = 6 * fi + comp;
    {
      const int kc = ks >> 5, kk = ks & 31, gg = (kk >> 2) & 3;
      const int e = (kk & 3) + 4 * (kk >> 4);
      swX[(((mt * 2 + kc) * 64 + gg * 16 + rr) << 3) + e] = (hf)sv;
    }
    {
      const int kco = ks + 3;
      const int kc = kco >> 5, kk = kco & 31, gg = (kk >> 2) & 3;
      const int e = (kk & 3) + 4 * (kk >> 4);
      swX[(((mt * 2 + kc) * 64 + gg * 16 + rr) << 3) + e] = (hf)cv;
    }
  }
  __syncthreads();

  // fc_pos via MFMA, A-fragments from LDS
  f32x4 acc[4][4];
#pragma unroll
  for (int nf = 0; nf < 4; ++nf) {
    float bv = bpos[wv * 64 + nf * 16 + r];
#pragma unroll
    for (int mf = 0; mf < 4; ++mf) acc[mf][nf] = splat4(bv);
  }
#pragma unroll
  for (int kc = 0; kc < 2; ++kc) {
    hf8 a[4];
#pragma unroll
    for (int mf = 0; mf < 4; ++mf)
      a[mf] = *(const hf8*)(swX + (((mf * 2 + kc) * 64 + lane) << 3));
#pragma unroll
    for (int nf = 0; nf < 4; ++nf) {
      hf8 b = ldfrag(fr + OFF_WPOS, kc, wv * 4 + nf, 16, lane);
#pragma unroll
      for (int mf = 0; mf < 4; ++mf) acc[mf][nf] = MFMA16(a[mf], b, acc[mf][nf]);
    }
  }
  __syncthreads();   // enc region dead; X-store below overwrites it

  // X -> frag-linear LDS, swizzled slot
#pragma unroll
  for (int mf = 0; mf < 4; ++mf)
#pragma unroll
    for (int nf = 0; nf < 4; ++nf)
#pragma unroll
      for (int reg = 0; reg < 4; ++reg) {
        int rr = 4 * g + reg;
        int c  = wv * 64 + nf * 16 + r;
        int kc = c >> 5;
        int kk = c & 31;
        int gg = (kk >> 2) & 3;
        int e  = (kk & 3) + 4 * (kk >> 4);
        int slot = gg * 16 + ((rr + gg) & 15);
        swX[(((size_t)(mf * 8 + kc) * 64 + slot) << 3) + e] = (hf)acc[mf][nf][reg];
      }
  __syncthreads();

  const int wm = wv >> 1, wn = wv & 1;
  const int lidx = g * 16 + ((r + g) & 15);

  f32x4 h[2][4], d[2][4];
#pragma unroll
  for (int nf = 0; nf < 4; ++nf) {
    const int n = wn * 64 + nf * 16 + r;
    const float bh = b0[n], bd = b1[n];
#pragma unroll
    for (int mf = 0; mf < 2; ++mf) { h[mf][nf] = splat4(bh); d[mf][nf] = splat4(bd); }
  }
#pragma unroll 2
  for (int kc = 0; kc < 8; ++kc) {
    hf8 a[2], ar[2];
#pragma unroll
    for (int mf = 0; mf < 2; ++mf) {
      a[mf] = *(const hf8*)(swX + (((size_t)((wm * 2 + mf) * 8 + kc) * 64 + lidx) << 3));
      ar[mf] = relu8(a[mf]);
    }
#pragma unroll
    for (int nf = 0; nf < 4; ++nf) {
      hf8 bw0 = ldfrag(w0f, kc, wn * 4 + nf, 8, lane);
      hf8 bws = ldfrag(wscf, kc, wn * 4 + nf, 8, lane);
#pragma unroll
      for (int mf = 0; mf < 2; ++mf) {
        h[mf][nf] = MFMA16(ar[mf], bw0, h[mf][nf]);
        d[mf][nf] = MFMA16(a[mf],  bws, d[mf][nf]);
      }
    }
  }
  __syncthreads();

#pragma unroll
  for (int mf = 0; mf < 2; ++mf)
#pragma unroll
    for (int nf = 0; nf < 4; ++nf)
#pragma unroll
      for (int reg = 0; reg < 4; ++reg) {
        int m = wm * 32 + mf * 16 + 4 * g + reg;
        int k = wn * 64 + nf * 16 + r;
        float hv = fmaxf(h[mf][nf][reg], 0.f);
        int mt = m >> 4, rr = m & 15;
        int kc = k >> 5, kk = k & 31;
        int gg = (kk >> 2) & 3;
        int e = (kk & 3) + 4 * (kk >> 4);
        int slot = gg * 16 + ((rr + gg) & 15);
        swX[(((size_t)(mt * 4 + kc) * 64 + slot) << 3) + e] = (hf)hv;
      }
  __syncthreads();

#pragma unroll
  for (int kc = 0; kc < 4; ++kc) {
    hf8 a[2];
#pragma unroll
    for (int mf = 0; mf < 2; ++mf)
      a[mf] = *(const hf8*)(swX + (((size_t)((wm * 2 + mf) * 4 + kc) * 64 + lidx) << 3));
#pragma unroll
    for (int nf = 0; nf < 4; ++nf) {
      hf8 bw1 = ldfrag(w1f, kc, wn * 4 + nf, 8, lane);
#pragma unroll
      for (int mf = 0; mf < 2; ++mf) d[mf][nf] = MFMA16(a[mf], bw1, d[mf][nf]);
    }
  }

#pragma unroll
  for (int mf = 0; mf < 2; ++mf)
#pragma unroll
    for (int nf = 0; nf < 4; ++nf)
#pragma unroll
      for (int reg = 0; reg < 4; ++reg) {
        int m = wm * 32 + mf * 16 + 4 * g + reg;
        int n = wn * 64 + nf * 16 + r;
        net[(size_t)sp[m] * 128 + n] = (hf)d[mf][nf][reg];
      }
}

// ---------------- pool (fallback path only): streaming segmented max --------
__global__ __launch_bounds__(256) void k_pool(
    const hf* __restrict__ net, const int* __restrict__ svox,
    hf* __restrict__ fea)
{
  const int tid = threadIdx.x;
  const int grp = tid >> 4, q = tid & 15;
  const int gbeg = blockIdx.x * 128 + grp * 8;
  const int gend = gbeg + 8;
  int i = gbeg;
  while (i < gend) {
    const int v = svox[i];
    if (i != 0 && svox[i - 1] == v) { ++i; continue; }
    float m[8];
#pragma unroll
    for (int e = 0; e < 8; ++e) m[e] = -1e30f;
    int j = i;
    do {
      union { uint4 u; hf h[8]; } x;
      x.u = *(const uint4*)(net + (size_t)j * 128 + 8 * q);
#pragma unroll
      for (int e = 0; e < 8; ++e) m[e] = fmaxf(m[e], (float)x.h[e]);
      ++j;
    } while (j < NPTS && svox[j] == v);
    union { uint4 u; hf h[8]; } o;
#pragma unroll
    for (int e = 0; e < 8; ++e) o.h[e] = (hf)m[e];
    *(uint4*)(fea + ((size_t)v << 7) + 8 * q) = o.u;
    i = j;
  }
}

// ---- ResnetBlockFC for 128 sorted points via MFMA (64KB LDS). --------------
// POOLIN=1: pooled X-half computed in-kernel via CSR segment walks over netin
//           (netin != netout ping-pong; no fea buffer, no k_pool).
// POOLIN=0: round-8 behavior (fea gather, in-place net).
// LAST=1:   fc_c fused at the tail.
template <int LAST, int POOLIN>
__global__ __launch_bounds__(256, 2) void k_res(
    const hf* __restrict__ netin, hf* __restrict__ netout,
    const hf* __restrict__ fea, const int* __restrict__ svox,
    const int* __restrict__ startb, const int* __restrict__ cnt,
    const hf* __restrict__ w0f, const hf* __restrict__ w1f,
    const hf* __restrict__ wscf,
    const float* __restrict__ b0, const float* __restrict__ b1,
    const hf* __restrict__ wcf, const float* __restrict__ bc)
{
  __shared__ __align__(16) hf swX[32768];   // 64 KB: X frags; H (32KB) aliases
  const int tid = threadIdx.x;
  const int wv = tid >> 6, lane = tid & 63;
  const int r = lane & 15, g = lane >> 4;
  const int wm = wv >> 1, wn = wv & 1;
  const int t0 = blockIdx.x * 128;
  const int lidx = g * 16 + ((r + g) & 15);

  if (POOLIN) {
    // lower half: net channels 0-127 of own rows
    for (int cc = tid; cc < 2048; cc += 256) {
      const int cl = cc & 63;
      const int kc = (cc >> 6) & 3;      // 0..3
      const int mt = cc >> 8;            // 0..7
      const int rr = cl & 15, gg = cl >> 4;
      const int t = t0 + mt * 16 + rr;
      const int c1 = kc * 32 + 4 * gg;
      union { hf8 h; uint2 u2[2]; } x;
      const hf* srcp = netin + (size_t)t * 128 + c1;
      x.u2[0] = *(const uint2*)(srcp);
      x.u2[1] = *(const uint2*)(srcp + 16);
      const int slot = gg * 16 + ((rr + gg) & 15);
      *(hf8*)(swX + (((size_t)((mt * 8 + kc) * 64 + slot)) << 3)) = x.h;
    }
    // upper half: pooled values via CSR segment walks (group = 8 rows x 8 ch)
    {
      const int grp = tid >> 4, q = tid & 15;
      const int rbase = t0 + grp * 8;
      int vprev = -1;
      float m[8];
#pragma unroll
      for (int e = 0; e < 8; ++e) m[e] = -1e30f;
      for (int rloc = 0; rloc < 8; ++rloc) {
        const int t = rbase + rloc;
        const int v = svox[t];
        if (v != vprev) {
          vprev = v;
          const int end = startb[v];
          const int beg = end - cnt[v];
#pragma unroll
          for (int e = 0; e < 8; ++e) m[e] = -1e30f;
          for (int j = beg; j < end; ++j) {
            union { uint4 u; hf h[8]; } x;
            x.u = *(const uint4*)(netin + (size_t)j * 128 + 8 * q);
#pragma unroll
            for (int e = 0; e < 8; ++e) m[e] = fmaxf(m[e], (float)x.h[e]);
          }
        }
        const int mt = (t - t0) >> 4, rr = (t - t0) & 15;
#pragma unroll
        for (int i = 0; i < 8; ++i) {
          const int c = 128 + 8 * q + i;
          const int kc = c >> 5;                    // 4..7
          const int kk = c & 31;
          const int gg = (kk >> 2) & 3;
          const int e = (kk & 3) + 4 * (kk >> 4);
          const int slot = gg * 16 + ((rr + gg) & 15);
          swX[(((size_t)((mt * 8 + kc) * 64 + slot)) << 3) + e] = (hf)m[i];
        }
      }
    }
  } else {
    for (int cc = tid; cc < 4096; cc += 256) {
      const int cl = cc & 63;
      const int kc = (cc >> 6) & 7;
      const int mt = cc >> 9;
      const int rr = cl & 15, gg = cl >> 4;
      const int t = t0 + mt * 16 + rr;
      const int c1 = kc * 32 + 4 * gg;
      union { hf8 h; uint2 u2[2]; } x;
      const hf* srcp;
      if (kc < 4) {
        srcp = netin + (size_t)t * 128 + c1;
      } else {
        srcp = fea + (((size_t)svox[t]) << 7) + (c1 - 128);
      }
      x.u2[0] = *(const uint2*)(srcp);
      x.u2[1] = *(const uint2*)(srcp + 16);
      const int slot = gg * 16 + ((rr + gg) & 15);
      *(hf8*)(swX + (((size_t)((cc & ~63) + slot)) << 3)) = x.h;
    }
  }
  __syncthreads();

  f32x4 h[4][4], d[4][4];
#pragma unroll
  for (int nf = 0; nf < 4; ++nf) {
    const int n = wn * 64 + nf * 16 + r;
    const float bh = b0[n], bd = b1[n];
#pragma unroll
    for (int mf = 0; mf < 4; ++mf) { h[mf][nf] = splat4(bh); d[mf][nf] = splat4(bd); }
  }
#pragma unroll 2
  for (int kc = 0; kc < 8; ++kc) {
    hf8 a[4], ar[4];
#pragma unroll
    for (int mf = 0; mf < 4; ++mf) {
      a[mf] = *(const hf8*)(swX + (((size_t)((wm * 4 + mf) * 8 + kc) * 64 + lidx) << 3));
      ar[mf] = relu8(a[mf]);
    }
#pragma unroll
    for (int nf = 0; nf < 4; ++nf) {
      hf8 bw0 = ldfrag(w0f, kc, wn * 4 + nf, 8, lane);
      hf8 bws = ldfrag(wscf, kc, wn * 4 + nf, 8, lane);
#pragma unroll
      for (int mf = 0; mf < 4; ++mf) {
        h[mf][nf] = MFMA16(ar[mf], bw0, h[mf][nf]);
        d[mf][nf] = MFMA16(a[mf],  bws, d[mf][nf]);
      }
    }
  }
  __syncthreads();

  // H = relu(h) -> swX[0..16384), swizzled
#pragma unroll
  for (int mf = 0; mf < 4; ++mf)
#pragma unroll
    for (int nf = 0; nf < 4; ++nf)
#pragma unroll
      for (int reg = 0; reg < 4; ++reg) {
        int m = wm * 64 + mf * 16 + 4 * g + reg;
        int k = wn * 64 + nf * 16 + r;
        float hv = fmaxf(h[mf][nf][reg], 0.f);
        int mt = m >> 4, rr = m & 15;
        int kc = k >> 5, kk = k & 31;
        int gg = (kk >> 2) & 3;
        int e = (kk & 3) + 4 * (kk >> 4);
        int slot = gg * 16 + ((rr + gg) & 15);
        swX[(((size_t)(mt * 4 + kc) * 64 + slot) << 3) + e] = (hf)hv;
      }
  __syncthreads();

#pragma unroll
  for (int kc = 0; kc < 4; ++kc) {
    hf8 a[4];
#pragma unroll
    for (int mf = 0; mf < 4; ++mf)
      a[mf] = *(const hf8*)(swX + (((size_t)((wm * 4 + mf) * 4 + kc) * 64 + lidx) << 3));
#pragma unroll
    for (int nf = 0; nf < 4; ++nf) {
      hf8 bw1 = ldfrag(w1f, kc, wn * 4 + nf, 8, lane);
#pragma unroll
      for (int mf = 0; mf < 4; ++mf) d[mf][nf] = MFMA16(a[mf], bw1, d[mf][nf]);
    }
  }

  if (LAST) {
    __syncthreads();
#pragma unroll
    for (int mf = 0; mf < 4; ++mf)
#pragma unroll
      for (int nf = 0; nf < 4; ++nf)
#pragma unroll
        for (int reg = 0; reg < 4; ++reg) {
          int m = wm * 64 + mf * 16 + 4 * g + reg;
          int k = wn * 64 + nf * 16 + r;
          int mt = m >> 4, rr = m & 15;
          int kc = k >> 5, kk = k & 31;
          int gg = (kk >> 2) & 3;
          int e = (kk & 3) + 4 * (kk >> 4);
          int slot = gg * 16 + ((rr + gg) & 15);
          swX[(((size_t)(mt * 4 + kc) * 64 + slot) << 3) + e] = (hf)d[mf][nf][reg];
        }
    __syncthreads();

    f32x4 c2[4][4];
#pragma unroll
    for (int nf = 0; nf < 4; ++nf) {
      float bv = bc[wn * 64 + nf * 16 + r];
#pragma unroll
      for (int mf = 0; mf < 4; ++mf) c2[mf][nf] = splat4(bv);
    }
#pragma unroll
    for (int kc = 0; kc < 4; ++kc) {
      hf8 a[4];
#pragma unroll
      for (int mf = 0; mf < 4; ++mf)
        a[mf] = *(const hf8*)(swX + (((size_t)((wm * 4 + mf) * 4 + kc) * 64 + lidx) << 3));
#pragma unroll
      for (int nf = 0; nf < 4; ++nf) {
        hf8 bw = ldfrag(wcf, kc, wn * 4 + nf, 8, lane);
#pragma unroll
        for (int mf = 0; mf < 4; ++mf) c2[mf][nf] = MFMA16(a[mf], bw, c2[mf][nf]);
      }
    }
#pragma unroll
    for (int mf = 0; mf < 4; ++mf)
#pragma unroll
      for (int nf = 0; nf < 4; ++nf)
#pragma unroll
        for (int reg = 0; reg < 4; ++reg) {
          int m = wm * 64 + mf * 16 + 4 * g + reg;
          int n = wn * 64 + nf * 16 + r;
          netout[(size_t)(t0 + m) * 128 + n] = (hf)c2[mf][nf][reg];
        }
  } else {
#pragma unroll
    for (int mf = 0; mf < 4; ++mf)
#pragma unroll
      for (int nf = 0; nf < 4; ++nf)
#pragma unroll
        for (int reg = 0; reg < 4; ++reg) {
          int m = wm * 64 + mf * 16 + 4 * g + reg;
          int n = wn * 64 + nf * 16 + r;
          netout[(size_t)(t0 + m) * 128 + n] = (hf)d[mf][nf][reg];
        }
  }
}

// ---------------- streaming gather-mean + transpose -------------------------
__global__ __launch_bounds__(256) void k_write(
    const hf* __restrict__ cbuf, const int* __restrict__ start,
    const int* __restrict__ cnt, float* __restrict__ out)
{
  __shared__ float tile[128 * 65];
  const int tid = threadIdx.x;
  const int grp = tid >> 4, q = tid & 15;
  const int g0 = blockIdx.x * 64;        // voxel base, (b<<15)|v0
  for (int vl = grp; vl < 64; vl += 16) {
    const int bv = g0 + vl;
    const int n = cnt[bv];
    const int end = start[bv], beg = end - n;
    float s[8] = {0, 0, 0, 0, 0, 0, 0, 0};
    for (int i = beg; i < end; ++i) {
      union { uint4 u; hf h[8]; } x;
      x.u = *(const uint4*)(cbuf + (size_t)i * 128 + 8 * q);
#pragma unroll
      for (int e = 0; e < 8; ++e) s[e] += (float)x.h[e];
    }
    const float inv = 1.0f / fmaxf((float)n, 1.0f);
#pragma unroll
    for (int e = 0; e < 8; ++e) tile[(8 * q + e) * 65 + vl] = s[e] * inv;
  }
  __syncthreads();
  const int b = g0 >> 15, v0 = g0 & 32767;
  for (int i = tid; i < 8192; i += 256) {
    const int c = i >> 6, vl = i & 63;
    out[(((size_t)(b * 128 + c)) << 15) + v0 + vl] = tile[c * 65 + vl];
  }
}

extern "C" void kernel_launch(void* const* d_in, const int* in_sizes, int n_in,
                              void* d_out, int out_size, void* d_ws, size_t ws_size,
                              hipStream_t stream)
{
  const float* p    = (const float*)d_in[0];
  const float* wpos = (const float*)d_in[1];
  const float* bpos = (const float*)d_in[2];
  const float* w0   = (const float*)d_in[3];
  const float* b0   = (const float*)d_in[4];
  const float* w1   = (const float*)d_in[5];
  const float* b1   = (const float*)d_in[6];
  const float* wsc  = (const float*)d_in[7];
  const float* wc   = (const float*)d_in[8];
  const float* bc   = (const float*)d_in[9];

  char* ws = (char*)d_ws;
  hf*  fr  = (hf*)d_out;  // weight frags; d_out fully overwritten by k_write

  // Big layout (ping-pong): idx 1M | netA 64M | netB 64M | cnt .5M | tot | start .5M | svox 1M
  const size_t OFF_IDX  = 0;
  const size_t OFF_NETA = (size_t)1u << 20;
  const size_t OFF_NETB = (size_t)65u << 20;
  const size_t OFF_CNT  = (size_t)129u << 20;
  const size_t OFF_TOT  = OFF_CNT + 0x80000;
  const size_t OFF_STR  = OFF_CNT + 0x80400;
  const size_t OFF_SVX  = OFF_CNT + 0x100400;
  const size_t NEED     = OFF_SVX + ((size_t)1u << 20);
  const bool big = (ws_size >= NEED);

  int* idxbuf; hf* netA; hf* netB; hf* fea; int* cnt32; int* total; int* startb; int* svox;
  if (big) {
    idxbuf = (int*)(ws + OFF_IDX);
    netA   = (hf*)(ws + OFF_NETA);
    netB   = (hf*)(ws + OFF_NETB);
    fea    = nullptr;
    cnt32  = (int*)(ws + OFF_CNT);
    total  = (int*)(ws + OFF_TOT);
    startb = (int*)(ws + OFF_STR);
    svox   = (int*)(ws + OFF_SVX);
  } else {
    idxbuf = (int*)ws;
    netA   = (hf*)(ws + (1u << 20));
    netB   = netA;                          // in-place
    fea    = (hf*)(ws + (65u << 20));       // 32 MiB
    cnt32  = (int*)(ws + (97u << 20));
    total  = (int*)(ws + (97u << 20) + 0x80000);
    startb = (int*)(ws + (97u << 20) + 0x80400);
    svox   = (int*)(ws + (97u << 20) + 0x100400);
  }

  k_prep<<<216, 256, 0, stream>>>(wpos, w0, w1, wsc, wc, fr);

  hipMemsetAsync(cnt32, 0, 0x80000 + 0x400, stream);
  k_idxcnt<<<NPTS / 256, 256, 0, stream>>>(p, idxbuf, cnt32);
  k_scan<<<NVOX / 512, 256, 0, stream>>>(cnt32, startb, total);
  k_fill<<<NPTS / 256, 256, 0, stream>>>(idxbuf, startb, svox);

  k_fused0<<<NPTS / 64, 256, 0, stream>>>(p, fr, bpos,
      fr + OFF_W0, fr + OFF_W1, fr + OFF_WSC, b0, b1, idxbuf, netA);

  if (big) {
    hf* bufs[2] = { netA, netB };
    for (int i = 1; i < 4; ++i) {
      k_res<0, 1><<<NPTS / 128, 256, 0, stream>>>(
          bufs[(i + 1) & 1], bufs[i & 1], nullptr, svox, startb, cnt32,
          fr + OFF_W0 + (size_t)i * 32768, fr + OFF_W1 + (size_t)i * 16384,
          fr + OFF_WSC + (size_t)i * 32768, b0 + i * 128, b1 + i * 128,
          nullptr, nullptr);
    }
    // i=4: B -> A (LAST, fc_c fused)
    k_res<1, 1><<<NPTS / 128, 256, 0, stream>>>(
        netB, netA, nullptr, svox, startb, cnt32,
        fr + OFF_W0 + (size_t)4 * 32768, fr + OFF_W1 + (size_t)4 * 16384,
        fr + OFF_WSC + (size_t)4 * 32768, b0 + 4 * 128, b1 + 4 * 128,
        fr + OFF_WC, bc);
  } else {
    for (int i = 1; i < 4; ++i) {
      k_pool<<<NPTS / 128, 256, 0, stream>>>(netA, svox, fea);
      k_res<0, 0><<<NPTS / 128, 256, 0, stream>>>(
          netA, netA, fea, svox, startb, cnt32,
          fr + OFF_W0 + (size_t)i * 32768, fr + OFF_W1 + (size_t)i * 16384,
          fr + OFF_WSC + (size_t)i * 32768, b0 + i * 128, b1 + i * 128,
          nullptr, nullptr);
    }
    k_pool<<<NPTS / 128, 256, 0, stream>>>(netA, svox, fea);
    k_res<1, 0><<<NPTS / 128, 256, 0, stream>>>(
        netA, netA, fea, svox, startb, cnt32,
        fr + OFF_W0 + (size_t)4 * 32768, fr + OFF_W1 + (size_t)4 * 16384,
        fr + OFF_WSC + (size_t)4 * 32768, b0 + 4 * 128, b1 + 4 * 128,
        fr + OFF_WC, bc);
  }

  k_write<<<NVOX / 64, 256, 0, stream>>>(netA, startb, cnt32, (float*)d_out);
}